// Round 8
// baseline (95.615 us; speedup 1.0000x reference)
//
#include <hip/hip_runtime.h>
#include <math.h>

#define T_LEN 4096
#define D_IN 128
#define HID 64
#define KDIM 4096   // TR*CTX
#define K2   8192   // re+im

// ws float offsets
#define OFF_GATED 0u
#define OFF_GO    262144u
#define OFF_SKIP  524288u
#define OFF_PART  786432u          // 8 * 262144 partials (also scan-carry scratch)
#define OFF_FLAGS 2883584u         // 4096 ints
#define OFF_CHS   2887680u         // 64 ints
#define OFF_WZT   2887744u         // 524288 bf16 = 262144 float slots
#define OFF_STBF  3149888u         // 4096*8192 bf16 = 16777216 float slots

typedef __attribute__((ext_vector_type(8))) short short8v;
typedef __attribute__((ext_vector_type(4))) float float4v;

__device__ __forceinline__ float sigm(float x){ return 1.f/(1.f+expf(-x)); }
__device__ __forceinline__ unsigned short f2bf(float x){
    unsigned int u = __float_as_uint(x);
    return (unsigned short)((u + 0x7FFFu + ((u >> 16) & 1u)) >> 16);
}

// ---------------------------------------------------------------- prep: flags | wzt | mlp  (role by blockIdx)
__global__ __launch_bounds__(512) void k_prep(
    const unsigned char* __restrict__ su8, const int* __restrict__ si32,
    int* __restrict__ flags, int* __restrict__ chunkStart,
    const float* __restrict__ Wz, unsigned short* __restrict__ wzt,
    const float* __restrict__ x,
    const float* __restrict__ W1, const float* __restrict__ b1,
    const float* __restrict__ W2, const float* __restrict__ b2,
    const float* __restrict__ Wgi, const float* __restrict__ bgi,
    const float* __restrict__ Wp,  const float* __restrict__ bp,
    const float* __restrict__ Wgo, const float* __restrict__ bgo,
    const float* __restrict__ Wsk, const float* __restrict__ bsk,
    float* __restrict__ gated, float* __restrict__ go, float* __restrict__ sk)
{
    const int bx = blockIdx.x;
    const int tid = threadIdx.x;

    if (bx == 0) {
        // ---------------- flags
        __shared__ int cnt;
        if (tid == 0) cnt = 0;
        __syncthreads();
        int local = 0;
        for (int i = tid; i < 4096; i += 512)
            if (i & 3) local += su8[i];
        if (local) atomicAdd(&cnt, local);
        __syncthreads();
        if (cnt > 0) {      // byte/bool storage
            for (int i = tid; i < 4096; i += 512) flags[i] = su8[i] ? 1 : 0;
        } else {            // int32 storage
            for (int i = tid; i < 4096; i += 512) flags[i] = si32[i] ? 1 : 0;
        }
        __syncthreads();
        if (tid < 64) {
            int any = 0;
#pragma unroll 8
            for (int j = 0; j < 64; ++j) any |= flags[tid * 64 + j];
            chunkStart[tid] = any;
        }
        return;
    }
    if (bx <= 64) {
        // ---------------- wzt: identity bf16 transpose  wzt[j][k] = Wz[k][j]
        int idx = ((bx - 1) * 512 + tid) * 16;
        int j = idx >> 13, k0 = idx & 8191;
#pragma unroll
        for (int e = 0; e < 16; ++e) {
            int k = k0 + e;
            wzt[(size_t)j * K2 + k] = f2bf(Wz[(size_t)k * 64 + j]);
        }
        return;
    }

    // ---------------- mlp: 8 rows per block, weights-in-VGPR
    __shared__ float xs[8][128];
    __shared__ float hs[8][64];
    __shared__ float h2s[8][128];
    __shared__ float tmp[8][4][64];
    const int t0 = (bx - 65) * 8;

    if (tid < 256) {
        int r = tid >> 5, kq = (tid & 31) << 2;
        *(float4*)&xs[r][kq] = *(const float4*)&x[(size_t)(t0 + r) * D_IN + kq];
    }

    // phase 1: h = relu(x@W1+b1). j1 in [0,64), ks1 = tid&7
    const int j1 = tid >> 3, ks1 = tid & 7;
    float wr1[16];
#pragma unroll
    for (int kk = 0; kk < 16; ++kk) wr1[kk] = W1[(size_t)(ks1 * 16 + kk) * HID + j1];
    const float bias1 = b1[j1];
    __syncthreads();
#pragma unroll
    for (int r = 0; r < 8; ++r) {
        float p = 0.f;
#pragma unroll
        for (int kq = 0; kq < 4; ++kq) {
            float4 xv = *(const float4*)&xs[r][ks1 * 16 + kq * 4];
            p += xv.x * wr1[kq*4] + xv.y * wr1[kq*4+1] + xv.z * wr1[kq*4+2] + xv.w * wr1[kq*4+3];
        }
        p += __shfl_xor(p, 1, 64); p += __shfl_xor(p, 2, 64); p += __shfl_xor(p, 4, 64);
        if (ks1 == 0) hs[r][j1] = fmaxf(p + bias1, 0.f);
    }

    // phase 2: h2 = h@W2+b2. j2 in [0,128), ks2 = tid&3
    const int j2 = tid >> 2, ks2 = tid & 3;
    float wr2[16];
#pragma unroll
    for (int kk = 0; kk < 16; ++kk) wr2[kk] = W2[(size_t)(ks2 * 16 + kk) * 128 + j2];
    const float bias2 = b2[j2];
    __syncthreads();
#pragma unroll
    for (int r = 0; r < 8; ++r) {
        float p = 0.f;
#pragma unroll
        for (int kq = 0; kq < 4; ++kq) {
            float4 hv = *(const float4*)&hs[r][ks2 * 16 + kq * 4];
            p += hv.x * wr2[kq*4] + hv.y * wr2[kq*4+1] + hv.z * wr2[kq*4+2] + hv.w * wr2[kq*4+3];
        }
        p += __shfl_xor(p, 1, 64); p += __shfl_xor(p, 2, 64);
        if (ks2 == 0) h2s[r][j2] = p + bias2;
    }

    // phase 3: four gate GEMMs (128->64). mat = tid>>7 (wave-uniform), jj, kh
    const int mat = tid >> 7, jj = (tid & 127) >> 1, kh = tid & 1;
    const float* Wm = (mat == 0) ? Wgi : (mat == 1) ? Wp : (mat == 2) ? Wgo : Wsk;
    float wgr[64];
#pragma unroll
    for (int kk = 0; kk < 64; ++kk) wgr[kk] = Wm[(size_t)(kh * 64 + kk) * 64 + jj];
    __syncthreads();
#pragma unroll
    for (int r = 0; r < 8; ++r) {
        float p = 0.f;
#pragma unroll
        for (int kq = 0; kq < 16; ++kq) {
            float4 hv = *(const float4*)&h2s[r][kh * 64 + kq * 4];
            p += hv.x * wgr[kq*4] + hv.y * wgr[kq*4+1] + hv.z * wgr[kq*4+2] + hv.w * wgr[kq*4+3];
        }
        p += __shfl_xor(p, 1, 64);
        if (kh == 0) tmp[r][mat][jj] = p;
    }
    __syncthreads();

    // finalize
    {
        int r = tid >> 6, j = tid & 63;
        int t = t0 + r;
        float gi = sigm(tmp[r][0][j] + bgi[j]);
        float pr = sigm(tmp[r][1][j] + bp[j]);
        float g  = sigm(tmp[r][2][j] + bgo[j]);
        float s  = tmp[r][3][j] + bsk[j];
        gated[t * 64 + j] = gi * pr;
        go[t * 64 + j]    = g;
        sk[t * 64 + j]    = s;
    }
}

// ---------------------------------------------------------------- scan A: per-chunk local carries (8 chains/block)
__global__ __launch_bounds__(512) void k_scanA(
    const float* __restrict__ gated, const int* __restrict__ flags,
    const float* __restrict__ a, const float* __restrict__ b,
    float2* __restrict__ carryB)
{
    const int p = threadIdx.x >> 6, c = threadIdx.x & 63;
    const int pair = blockIdx.x * 8 + p;
    const int ch = pair & 63, m = pair >> 6;
    const int t0 = ch * 64;
    __shared__ float gb[8][64];
    __shared__ int fb[8][64];
    gb[p][c] = gated[(size_t)(t0 + c) * 64 + m];
    fb[p][c] = flags[t0 + c];
    __syncthreads();

    const double ea = exp(-fabs((double)a[m]));
    const double bb = (double)b[c];
    const double lre = ea * cos(bb), lim = ea * sin(bb);
    double sre = 0.0, sim = 0.0;
#pragma unroll 8
    for (int j = 0; j < 64; ++j) {
        double g = (double)gb[p][j];
        if (fb[p][j]) { sre = g; sim = 0.0; }
        else {
            double nr = fma(sre, lre, fma(-sim, lim, g));
            double ni = fma(sre, lim, sim * lre);
            sre = nr; sim = ni;
        }
    }
    carryB[(size_t)ch * KDIM + m * 64 + c] = make_float2((float)sre, (float)sim);
}

// ---------------------------------------------------------------- scan C: carry scan over chunks (register-pipelined)
__global__ __launch_bounds__(64) void k_scanC(
    const float2* __restrict__ carryB, const int* __restrict__ chunkStart,
    const float* __restrict__ a, const float* __restrict__ b,
    const float* __restrict__ st0,
    float2* __restrict__ cinArr)
{
    const int m = blockIdx.x, c = threadIdx.x;
    __shared__ int chsS[64];
    chsS[c] = chunkStart[c];

    float2 Bv[64];
#pragma unroll
    for (int ch = 0; ch < 64; ++ch)
        Bv[ch] = carryB[(size_t)ch * KDIM + m * 64 + c];
    __syncthreads();

    const double ea64 = exp(-64.0 * fabs((double)a[m]));
    const double bb = (double)b[c];
    const double l64re = ea64 * cos(64.0 * bb), l64im = ea64 * sin(64.0 * bb);
    double cre = (double)st0[(m * 64 + c) * 2];
    double cim = (double)st0[(m * 64 + c) * 2 + 1];
#pragma unroll
    for (int ch = 0; ch < 64; ++ch) {
        cinArr[(size_t)ch * KDIM + m * 64 + c] = make_float2((float)cre, (float)cim);
        if (chsS[ch]) { cre = (double)Bv[ch].x; cim = (double)Bv[ch].y; }
        else {
            double nr = fma(cre, l64re, fma(-cim, l64im, (double)Bv[ch].x));
            double ni = fma(cre, l64im, fma(cim, l64re, (double)Bv[ch].y));
            cre = nr; cim = ni;
        }
    }
}

// ---------------------------------------------------------------- scan B: seeded rerun -> LDS tile -> coalesced bf16 store
// grid: 1024 blocks = (ch 0..63) x (mg 0..15); 256 thr = (ml 0..3) x (c 0..63); m = mg*4+ml
// state layout: stbf[t][k], k = m*128 + c (re) | m*128 + 64 + c (im)   [matches Wz row order]
__global__ __launch_bounds__(256) void k_scanB(
    const float* __restrict__ gated, const int* __restrict__ flags,
    const float* __restrict__ a, const float* __restrict__ b,
    const float2* __restrict__ cinArr,
    unsigned short* __restrict__ stbf,
    float* __restrict__ out)
{
    const int tid = threadIdx.x;
    const int ml = tid >> 6, c = tid & 63;
    const int ch = blockIdx.x & 63, mg = blockIdx.x >> 6;
    const int m = mg * 4 + ml;
    const int t0 = ch * 64;
    __shared__ unsigned short st[64][512];   // 64KB
    __shared__ float gb[4][64];
    __shared__ int fb[64];
    gb[ml][c] = gated[(size_t)(t0 + c) * 64 + m];
    if (ml == 0) fb[c] = flags[t0 + c];
    __syncthreads();

    const double ea = exp(-fabs((double)a[m]));
    const double bb = (double)b[c];
    const double lre = ea * cos(bb), lim = ea * sin(bb);
    float2 cin = cinArr[(size_t)ch * KDIM + m * 64 + c];
    double sre = (double)cin.x, sim = (double)cin.y;
#pragma unroll 4
    for (int j = 0; j < 64; ++j) {
        double g = (double)gb[ml][j];
        if (fb[j]) { sre = g; sim = 0.0; }
        else {
            double nr = fma(sre, lre, fma(-sim, lim, g));
            double ni = fma(sre, lim, sim * lre);
            sre = nr; sim = ni;
        }
        st[j][ml * 128 + c]      = f2bf((float)sre);
        st[j][ml * 128 + 64 + c] = f2bf((float)sim);
    }
    __syncthreads();

    // coalesced flush: 64 rows x 1KB = 4096 x 16B chunks -> 16 iterations of 256 threads
#pragma unroll
    for (int it = 0; it < 16; ++it) {
        int idx = it * 256 + tid;
        int row = idx >> 6, colB = (idx & 63) * 16;
        *(uint4*)((char*)(stbf + (size_t)(t0 + row) * K2 + mg * 512) + colB) =
            *(const uint4*)((const char*)st + row * 1024 + colB);
    }
    if (ch == 63) {   // t = 4095: final state, planar f32 (m*64+c indexing)
        out[524288 + m * 64 + c]        = (float)sre;
        out[524288 + 4096 + m * 64 + c] = (float)sim;
    }
}

// ---------------------------------------------------------------- z GEMM: bf16 MFMA, M-tile 64, K-split x8, double-buffered
__global__ __launch_bounds__(256) void k_zgemm(
    const unsigned short* __restrict__ stbf,
    const unsigned short* __restrict__ wzt,
    float* __restrict__ part)
{
    __shared__ char smem[65536];   // [2] x { A 16KB | B 16KB }
    const int tid = threadIdx.x;
    const int w = tid >> 6, l = tid & 63;
    const int mb = blockIdx.x >> 3, kb = blockIdx.x & 7;
    const int kbase = kb * 1024;

    float4v acc[4];
#pragma unroll
    for (int i = 0; i < 4; ++i) acc[i] = (float4v){0.f, 0.f, 0.f, 0.f};

#define ZSTAGE(s, d)                                                                              \
    _Pragma("unroll")                                                                             \
    for (int it = 0; it < 4; ++it) {                                                              \
        int ci = it * 256 + tid;                                                                  \
        int r = ci >> 4, pc = ci & 15;                                                            \
        int gc = pc ^ (r & 7);                                                                    \
        const unsigned short* gpA = stbf + (size_t)(mb * 64 + r) * K2 + kbase + (s) * 128 + gc * 8;\
        const unsigned short* gpB = wzt + (size_t)r * K2 + kbase + (s) * 128 + gc * 8;            \
        __builtin_amdgcn_global_load_lds(                                                         \
            (const __attribute__((address_space(1))) void*)gpA,                                   \
            (__attribute__((address_space(3))) void*)(smem + (d) * 32768 + ci * 16), 16, 0, 0);   \
        __builtin_amdgcn_global_load_lds(                                                         \
            (const __attribute__((address_space(1))) void*)gpB,                                   \
            (__attribute__((address_space(3))) void*)(smem + (d) * 32768 + 16384 + ci * 16), 16, 0, 0); \
    }

    ZSTAGE(0, 0);
    __syncthreads();
    const int row_l = w * 16 + (l & 15);
    const int swz = (l & 7) << 4;
    const int ksub = (l >> 4) * 16;
#pragma unroll
    for (int s = 0; s < 8; ++s) {
        const int cur = s & 1;
        if (s < 7) { ZSTAGE(s + 1, cur ^ 1); }          // prefetch next step (overlaps MFMA)
        const char* bufA = smem + cur * 32768;
        const char* bufB = bufA + 16384;
#pragma unroll
        for (int k32 = 0; k32 < 4; ++k32) {
            int kbyte = k32 * 64 + ksub;
            short8v af = *(const short8v*)(bufA + row_l * 256 + (kbyte ^ swz));
#pragma unroll
            for (int nt = 0; nt < 4; ++nt) {
                int row_b = nt * 16 + (l & 15);
                short8v bf = *(const short8v*)(bufB + row_b * 256 + (kbyte ^ swz));
                acc[nt] = __builtin_amdgcn_mfma_f32_16x16x32_bf16(af, bf, acc[nt], 0, 0, 0);
            }
        }
        __syncthreads();                                 // drains prefetch + guards buf reuse
    }
#undef ZSTAGE

    float* pp = part + (size_t)kb * 262144;
    const int trow = mb * 64 + w * 16 + (l >> 4) * 4;
    const int jcol = l & 15;
#pragma unroll
    for (int nt = 0; nt < 4; ++nt)
#pragma unroll
        for (int r = 0; r < 4; ++r)
            pp[(size_t)(trow + r) * 64 + nt * 16 + jcol] = acc[nt][r];
}

// ---------------------------------------------------------------- epilogue
__device__ __forceinline__ float wsum(float v) {
#pragma unroll
    for (int o = 32; o; o >>= 1) v += __shfl_xor(v, o, 64);
    return v;
}

__global__ __launch_bounds__(256) void k_epi(
    const float* __restrict__ part, const float* __restrict__ bz,
    const float* __restrict__ go, const float* __restrict__ sk,
    const float* __restrict__ W3, const float* __restrict__ b3,
    const float* __restrict__ W4, const float* __restrict__ b4,
    float* __restrict__ out)
{
    __shared__ float ob[4][64], hb[4][64];
    const int w = threadIdx.x >> 6, j = threadIdx.x & 63;
    const int t = blockIdx.x * 4 + w;
    float z = bz[j];
#pragma unroll
    for (int p = 0; p < 8; ++p) z += part[(size_t)p * 262144 + t * 64 + j];
    float g = go[t * 64 + j];
    float y = z * g;
    float mu = wsum(y) * 0.015625f;
    float d = y - mu;
    float var = wsum(d * d) * 0.015625f;
    float o = d * (1.f / sqrtf(var + 1e-6f)) + sk[t * 64 + j] * (1.f - g);
    ob[w][j] = o;
    __syncthreads();
    float acc = b3[j];
#pragma unroll 8
    for (int k = 0; k < 64; ++k) acc += ob[w][k] * W3[k * 64 + j];
    hb[w][j] = fmaxf(acc, 0.f);
    __syncthreads();
    float o1 = b4[j], o2 = b4[j + 64];
#pragma unroll 8
    for (int k = 0; k < 64; ++k) { float hv = hb[w][k]; o1 += hv * W4[k * 128 + j]; o2 += hv * W4[k * 128 + j + 64]; }
    out[(size_t)t * 128 + j] = o1;
    out[(size_t)t * 128 + j + 64] = o2;
}

// ----------------------------------------------------------------
extern "C" void kernel_launch(void* const* d_in, const int* in_sizes, int n_in,
                              void* d_out, int out_size, void* d_ws, size_t ws_size,
                              hipStream_t stream)
{
    const float* x   = (const float*)d_in[0];
    const float* st0 = (const float*)d_in[1];
    const void*  start = d_in[2];
    const float* a  = (const float*)d_in[3];
    const float* b  = (const float*)d_in[4];
    const float* W1 = (const float*)d_in[5];  const float* b1 = (const float*)d_in[6];
    const float* W2 = (const float*)d_in[7];  const float* b2 = (const float*)d_in[8];
    const float* Wgi= (const float*)d_in[9];  const float* bgi= (const float*)d_in[10];
    const float* Wp = (const float*)d_in[11]; const float* bp = (const float*)d_in[12];
    const float* Wz = (const float*)d_in[13]; const float* bz = (const float*)d_in[14];
    const float* Wgo= (const float*)d_in[15]; const float* bgo= (const float*)d_in[16];
    const float* Wsk= (const float*)d_in[17]; const float* bsk= (const float*)d_in[18];
    const float* W3 = (const float*)d_in[19]; const float* b3 = (const float*)d_in[20];
    const float* W4 = (const float*)d_in[21]; const float* b4 = (const float*)d_in[22];

    float* ws    = (float*)d_ws;
    float* out   = (float*)d_out;
    float* gated = ws + OFF_GATED;
    float* go    = ws + OFF_GO;
    float* sk    = ws + OFF_SKIP;
    float* part  = ws + OFF_PART;
    int*   flags = (int*)(ws + OFF_FLAGS);
    int*   chs   = (int*)(ws + OFF_CHS);
    unsigned short* wzt  = (unsigned short*)(ws + OFF_WZT);
    unsigned short* stbf = (unsigned short*)(ws + OFF_STBF);

    float2* carryB = (float2*)(part);            // 524288 floats
    float2* cinArr = (float2*)(part + 524288);   // 524288 floats

    hipLaunchKernelGGL(k_prep, dim3(577), dim3(512), 0, stream,
                       (const unsigned char*)start, (const int*)start, flags, chs,
                       Wz, wzt, x, W1, b1, W2, b2, Wgi, bgi, Wp, bp,
                       Wgo, bgo, Wsk, bsk, gated, go, sk);
    hipLaunchKernelGGL(k_scanA, dim3(512), dim3(512), 0, stream,
                       gated, flags, a, b, carryB);
    hipLaunchKernelGGL(k_scanC, dim3(64), dim3(64), 0, stream,
                       carryB, chs, a, b, st0, cinArr);
    hipLaunchKernelGGL(k_scanB, dim3(1024), dim3(256), 0, stream,
                       gated, flags, a, b, cinArr, stbf, out);
    hipLaunchKernelGGL(k_zgemm, dim3(512), dim3(256), 0, stream, stbf, wzt, part);
    hipLaunchKernelGGL(k_epi, dim3(1024), dim3(256), 0, stream,
                       part, bz, go, sk, W3, b3, W4, b4, out);
}

// Round 9
// 86.169 us; speedup vs baseline: 1.1096x; 1.1096x over previous
//
#include <hip/hip_runtime.h>
#include <math.h>

#define T_LEN 4096
#define D_IN 128
#define HID 64
#define KDIM 4096   // TR*CTX
#define K2   8192   // re+im

// ws float offsets
#define OFF_GATED 0u
#define OFF_GO    262144u
#define OFF_SKIP  524288u
#define OFF_PART  786432u          // 16 * 262144 partials
#define OFF_FLAGS 4980736u         // 4096 ints
#define OFF_CHS   4984832u         // 64 ints
#define OFF_WZT   4984896u         // 524288 bf16 = 262144 float slots
#define OFF_SCR   5247040u         // carryB 524288 + cinArr 524288 floats

typedef __attribute__((ext_vector_type(8))) short short8v;
typedef __attribute__((ext_vector_type(4))) float float4v;

__device__ __forceinline__ float sigm(float x){ return 1.f/(1.f+expf(-x)); }
__device__ __forceinline__ unsigned short f2bf(float x){
    unsigned int u = __float_as_uint(x);
    return (unsigned short)((u + 0x7FFFu + ((u >> 16) & 1u)) >> 16);
}

// ---------------------------------------------------------------- prep: flags | wzt | mlp  (role by blockIdx)
__global__ __launch_bounds__(512) void k_prep(
    const unsigned char* __restrict__ su8, const int* __restrict__ si32,
    int* __restrict__ flags, int* __restrict__ chunkStart,
    const float* __restrict__ Wz, unsigned short* __restrict__ wzt,
    const float* __restrict__ x,
    const float* __restrict__ W1, const float* __restrict__ b1,
    const float* __restrict__ W2, const float* __restrict__ b2,
    const float* __restrict__ Wgi, const float* __restrict__ bgi,
    const float* __restrict__ Wp,  const float* __restrict__ bp,
    const float* __restrict__ Wgo, const float* __restrict__ bgo,
    const float* __restrict__ Wsk, const float* __restrict__ bsk,
    float* __restrict__ gated, float* __restrict__ go, float* __restrict__ sk)
{
    const int bx = blockIdx.x;
    const int tid = threadIdx.x;

    if (bx == 0) {
        // ---------------- flags
        __shared__ int cnt;
        if (tid == 0) cnt = 0;
        __syncthreads();
        int local = 0;
        for (int i = tid; i < 4096; i += 512)
            if (i & 3) local += su8[i];
        if (local) atomicAdd(&cnt, local);
        __syncthreads();
        if (cnt > 0) {      // byte/bool storage
            for (int i = tid; i < 4096; i += 512) flags[i] = su8[i] ? 1 : 0;
        } else {            // int32 storage
            for (int i = tid; i < 4096; i += 512) flags[i] = si32[i] ? 1 : 0;
        }
        __syncthreads();
        if (tid < 64) {
            int any = 0;
#pragma unroll 8
            for (int j = 0; j < 64; ++j) any |= flags[tid * 64 + j];
            chunkStart[tid] = any;
        }
        return;
    }
    if (bx <= 64) {
        // ---------------- wzt: identity bf16 transpose  wzt[j][k] = Wz[k][j]
        int idx = ((bx - 1) * 512 + tid) * 16;
        int j = idx >> 13, k0 = idx & 8191;
#pragma unroll
        for (int e = 0; e < 16; ++e) {
            int k = k0 + e;
            wzt[(size_t)j * K2 + k] = f2bf(Wz[(size_t)k * 64 + j]);
        }
        return;
    }

    // ---------------- mlp: 8 rows per block, weights-in-VGPR
    __shared__ float xs[8][128];
    __shared__ float hs[8][64];
    __shared__ float h2s[8][128];
    __shared__ float tmp[8][4][64];
    const int t0 = (bx - 65) * 8;

    if (tid < 256) {
        int r = tid >> 5, kq = (tid & 31) << 2;
        *(float4*)&xs[r][kq] = *(const float4*)&x[(size_t)(t0 + r) * D_IN + kq];
    }

    // phase 1: h = relu(x@W1+b1). j1 in [0,64), ks1 = tid&7
    const int j1 = tid >> 3, ks1 = tid & 7;
    float wr1[16];
#pragma unroll
    for (int kk = 0; kk < 16; ++kk) wr1[kk] = W1[(size_t)(ks1 * 16 + kk) * HID + j1];
    const float bias1 = b1[j1];
    __syncthreads();
#pragma unroll
    for (int r = 0; r < 8; ++r) {
        float p = 0.f;
#pragma unroll
        for (int kq = 0; kq < 4; ++kq) {
            float4 xv = *(const float4*)&xs[r][ks1 * 16 + kq * 4];
            p += xv.x * wr1[kq*4] + xv.y * wr1[kq*4+1] + xv.z * wr1[kq*4+2] + xv.w * wr1[kq*4+3];
        }
        p += __shfl_xor(p, 1, 64); p += __shfl_xor(p, 2, 64); p += __shfl_xor(p, 4, 64);
        if (ks1 == 0) hs[r][j1] = fmaxf(p + bias1, 0.f);
    }

    // phase 2: h2 = h@W2+b2. j2 in [0,128), ks2 = tid&3
    const int j2 = tid >> 2, ks2 = tid & 3;
    float wr2[16];
#pragma unroll
    for (int kk = 0; kk < 16; ++kk) wr2[kk] = W2[(size_t)(ks2 * 16 + kk) * 128 + j2];
    const float bias2 = b2[j2];
    __syncthreads();
#pragma unroll
    for (int r = 0; r < 8; ++r) {
        float p = 0.f;
#pragma unroll
        for (int kq = 0; kq < 4; ++kq) {
            float4 hv = *(const float4*)&hs[r][ks2 * 16 + kq * 4];
            p += hv.x * wr2[kq*4] + hv.y * wr2[kq*4+1] + hv.z * wr2[kq*4+2] + hv.w * wr2[kq*4+3];
        }
        p += __shfl_xor(p, 1, 64); p += __shfl_xor(p, 2, 64);
        if (ks2 == 0) h2s[r][j2] = p + bias2;
    }

    // phase 3: four gate GEMMs (128->64). mat = tid>>7 (wave-uniform), jj, kh
    const int mat = tid >> 7, jj = (tid & 127) >> 1, kh = tid & 1;
    const float* Wm = (mat == 0) ? Wgi : (mat == 1) ? Wp : (mat == 2) ? Wgo : Wsk;
    float wgr[64];
#pragma unroll
    for (int kk = 0; kk < 64; ++kk) wgr[kk] = Wm[(size_t)(kh * 64 + kk) * 64 + jj];
    __syncthreads();
#pragma unroll
    for (int r = 0; r < 8; ++r) {
        float p = 0.f;
#pragma unroll
        for (int kq = 0; kq < 16; ++kq) {
            float4 hv = *(const float4*)&h2s[r][kh * 64 + kq * 4];
            p += hv.x * wgr[kq*4] + hv.y * wgr[kq*4+1] + hv.z * wgr[kq*4+2] + hv.w * wgr[kq*4+3];
        }
        p += __shfl_xor(p, 1, 64);
        if (kh == 0) tmp[r][mat][jj] = p;
    }
    __syncthreads();

    // finalize
    {
        int r = tid >> 6, j = tid & 63;
        int t = t0 + r;
        float gi = sigm(tmp[r][0][j] + bgi[j]);
        float pr = sigm(tmp[r][1][j] + bp[j]);
        float g  = sigm(tmp[r][2][j] + bgo[j]);
        float s  = tmp[r][3][j] + bsk[j];
        gated[t * 64 + j] = gi * pr;
        go[t * 64 + j]    = g;
        sk[t * 64 + j]    = s;
    }
}

// ---------------------------------------------------------------- scan A: per-chunk local carries (8 chains/block)
__global__ __launch_bounds__(512) void k_scanA(
    const float* __restrict__ gated, const int* __restrict__ flags,
    const float* __restrict__ a, const float* __restrict__ b,
    float2* __restrict__ carryB)
{
    const int p = threadIdx.x >> 6, c = threadIdx.x & 63;
    const int pair = blockIdx.x * 8 + p;
    const int ch = pair & 63, m = pair >> 6;
    const int t0 = ch * 64;
    __shared__ float gb[8][64];
    __shared__ int fb[8][64];
    gb[p][c] = gated[(size_t)(t0 + c) * 64 + m];
    fb[p][c] = flags[t0 + c];
    __syncthreads();

    const double ea = exp(-fabs((double)a[m]));
    const double bb = (double)b[c];
    const double lre = ea * cos(bb), lim = ea * sin(bb);
    double sre = 0.0, sim = 0.0;
#pragma unroll 8
    for (int j = 0; j < 64; ++j) {
        double g = (double)gb[p][j];
        if (fb[p][j]) { sre = g; sim = 0.0; }
        else {
            double nr = fma(sre, lre, fma(-sim, lim, g));
            double ni = fma(sre, lim, sim * lre);
            sre = nr; sim = ni;
        }
    }
    carryB[(size_t)ch * KDIM + m * 64 + c] = make_float2((float)sre, (float)sim);
}

// ---------------------------------------------------------------- scan C: carry scan over chunks (register-pipelined)
__global__ __launch_bounds__(64) void k_scanC(
    const float2* __restrict__ carryB, const int* __restrict__ chunkStart,
    const float* __restrict__ a, const float* __restrict__ b,
    const float* __restrict__ st0,
    float2* __restrict__ cinArr)
{
    const int m = blockIdx.x, c = threadIdx.x;
    __shared__ int chsS[64];
    chsS[c] = chunkStart[c];

    float2 Bv[64];
#pragma unroll
    for (int ch = 0; ch < 64; ++ch)
        Bv[ch] = carryB[(size_t)ch * KDIM + m * 64 + c];
    __syncthreads();

    const double ea64 = exp(-64.0 * fabs((double)a[m]));
    const double bb = (double)b[c];
    const double l64re = ea64 * cos(64.0 * bb), l64im = ea64 * sin(64.0 * bb);
    double cre = (double)st0[(m * 64 + c) * 2];
    double cim = (double)st0[(m * 64 + c) * 2 + 1];
#pragma unroll
    for (int ch = 0; ch < 64; ++ch) {
        cinArr[(size_t)ch * KDIM + m * 64 + c] = make_float2((float)cre, (float)cim);
        if (chsS[ch]) { cre = (double)Bv[ch].x; cim = (double)Bv[ch].y; }
        else {
            double nr = fma(cre, l64re, fma(-cim, l64im, (double)Bv[ch].x));
            double ni = fma(cre, l64im, fma(cim, l64re, (double)Bv[ch].y));
            cre = nr; cim = ni;
        }
    }
}

// ---------------------------------------------------------------- scan B + z GEMM fused
// grid: 1024 blocks = (ch 0..63) x (mg 0..15); 256 thr = 4 waves (ml) x 64 lanes (c)
// scan 4 m's into LDS bf16 tile st[64t][512k] (XOR-swizzled), then each wave
// MFMAs the tile against its wzt j-slice -> part[mg][ch*64+t][j]
__global__ __launch_bounds__(256) void k_scanBZ(
    const float* __restrict__ gated, const int* __restrict__ flags,
    const float* __restrict__ a, const float* __restrict__ b,
    const float2* __restrict__ cinArr,
    const unsigned short* __restrict__ wzt,
    float* __restrict__ part,
    float* __restrict__ out)
{
    const int tid = threadIdx.x;
    const int ml = tid >> 6, c = tid & 63;       // ml = wave index
    const int ch = blockIdx.x & 63, mg = blockIdx.x >> 6;
    const int m = mg * 4 + ml;
    const int t0 = ch * 64;
    __shared__ unsigned short st[64 * 512];      // 64KB, swizzled chunks of 8 elems
    __shared__ float gb[4][64];
    __shared__ int fb[64];
    gb[ml][c] = gated[(size_t)(t0 + c) * 64 + m];
    if (ml == 0) fb[c] = flags[t0 + c];
    __syncthreads();

    const double ea = exp(-fabs((double)a[m]));
    const double bb = (double)b[c];
    const double lre = ea * cos(bb), lim = ea * sin(bb);
    float2 cin = cinArr[(size_t)ch * KDIM + m * 64 + c];
    double sre = (double)cin.x, sim = (double)cin.y;
    const int e0 = ml * 128 + c, e1 = ml * 128 + 64 + c;
#pragma unroll 4
    for (int j = 0; j < 64; ++j) {
        double g = (double)gb[ml][j];
        if (fb[j]) { sre = g; sim = 0.0; }
        else {
            double nr = fma(sre, lre, fma(-sim, lim, g));
            double ni = fma(sre, lim, sim * lre);
            sre = nr; sim = ni;
        }
        const int sx = (j & 7) << 3;             // chunk-granular XOR swizzle
        st[j * 512 + (e0 ^ sx)] = f2bf((float)sre);
        st[j * 512 + (e1 ^ sx)] = f2bf((float)sim);
    }
    if (ch == 63) {   // t = 4095: final state, planar f32
        out[524288 + m * 64 + c]        = (float)sre;
        out[524288 + 4096 + m * 64 + c] = (float)sim;
    }

    // B fragments: wave ml covers j = ml*16 + (lane&15); 16 k-steps of 32 (L2-hot, issued pre-barrier)
    const int l = c;
    const int jrow = ml * 16 + (l & 15);
    short8v bfr[16];
#pragma unroll
    for (int ks = 0; ks < 16; ++ks)
        bfr[ks] = *(const short8v*)&wzt[(size_t)jrow * K2 + mg * 512 + (ks * 4 + (l >> 4)) * 8];

    __syncthreads();

    float4v acc[4];
#pragma unroll
    for (int i = 0; i < 4; ++i) acc[i] = (float4v){0.f, 0.f, 0.f, 0.f};
#pragma unroll
    for (int ks = 0; ks < 16; ++ks) {
#pragma unroll
        for (int mt = 0; mt < 4; ++mt) {
            const int row = mt * 16 + (l & 15);
            const int rchunk = (ks * 4 + (l >> 4)) ^ (row & 7);
            short8v af = *(const short8v*)&st[row * 512 + rchunk * 8];
            acc[mt] = __builtin_amdgcn_mfma_f32_16x16x32_bf16(af, bfr[ks], acc[mt], 0, 0, 0);
        }
    }

    // C/D: t-row = mt*16 + (lane>>4)*4 + r; j-col = ml*16 + (lane&15)
    float* pp = part + (size_t)mg * 262144;
    const int jcol = ml * 16 + (l & 15);
#pragma unroll
    for (int mt = 0; mt < 4; ++mt) {
        const int trow = t0 + mt * 16 + (l >> 4) * 4;
#pragma unroll
        for (int r = 0; r < 4; ++r)
            pp[(size_t)(trow + r) * 64 + jcol] = acc[mt][r];
    }
}

// ---------------------------------------------------------------- epilogue
__device__ __forceinline__ float wsum(float v) {
#pragma unroll
    for (int o = 32; o; o >>= 1) v += __shfl_xor(v, o, 64);
    return v;
}

__global__ __launch_bounds__(256) void k_epi(
    const float* __restrict__ part, const float* __restrict__ bz,
    const float* __restrict__ go, const float* __restrict__ sk,
    const float* __restrict__ W3, const float* __restrict__ b3,
    const float* __restrict__ W4, const float* __restrict__ b4,
    float* __restrict__ out)
{
    __shared__ float ob[4][64], hb[4][64];
    const int w = threadIdx.x >> 6, j = threadIdx.x & 63;
    const int t = blockIdx.x * 4 + w;
    float z = bz[j];
#pragma unroll
    for (int p = 0; p < 16; ++p) z += part[(size_t)p * 262144 + t * 64 + j];
    float g = go[t * 64 + j];
    float y = z * g;
    float mu = wsum(y) * 0.015625f;
    float d = y - mu;
    float var = wsum(d * d) * 0.015625f;
    float o = d * (1.f / sqrtf(var + 1e-6f)) + sk[t * 64 + j] * (1.f - g);
    ob[w][j] = o;
    __syncthreads();
    float acc = b3[j];
#pragma unroll 8
    for (int k = 0; k < 64; ++k) acc += ob[w][k] * W3[k * 64 + j];
    hb[w][j] = fmaxf(acc, 0.f);
    __syncthreads();
    float o1 = b4[j], o2 = b4[j + 64];
#pragma unroll 8
    for (int k = 0; k < 64; ++k) { float hv = hb[w][k]; o1 += hv * W4[k * 128 + j]; o2 += hv * W4[k * 128 + j + 64]; }
    out[(size_t)t * 128 + j] = o1;
    out[(size_t)t * 128 + j + 64] = o2;
}

// ----------------------------------------------------------------
extern "C" void kernel_launch(void* const* d_in, const int* in_sizes, int n_in,
                              void* d_out, int out_size, void* d_ws, size_t ws_size,
                              hipStream_t stream)
{
    const float* x   = (const float*)d_in[0];
    const float* st0 = (const float*)d_in[1];
    const void*  start = d_in[2];
    const float* a  = (const float*)d_in[3];
    const float* b  = (const float*)d_in[4];
    const float* W1 = (const float*)d_in[5];  const float* b1 = (const float*)d_in[6];
    const float* W2 = (const float*)d_in[7];  const float* b2 = (const float*)d_in[8];
    const float* Wgi= (const float*)d_in[9];  const float* bgi= (const float*)d_in[10];
    const float* Wp = (const float*)d_in[11]; const float* bp = (const float*)d_in[12];
    const float* Wz = (const float*)d_in[13]; const float* bz = (const float*)d_in[14];
    const float* Wgo= (const float*)d_in[15]; const float* bgo= (const float*)d_in[16];
    const float* Wsk= (const float*)d_in[17]; const float* bsk= (const float*)d_in[18];
    const float* W3 = (const float*)d_in[19]; const float* b3 = (const float*)d_in[20];
    const float* W4 = (const float*)d_in[21]; const float* b4 = (const float*)d_in[22];

    float* ws    = (float*)d_ws;
    float* out   = (float*)d_out;
    float* gated = ws + OFF_GATED;
    float* go    = ws + OFF_GO;
    float* sk    = ws + OFF_SKIP;
    float* part  = ws + OFF_PART;
    int*   flags = (int*)(ws + OFF_FLAGS);
    int*   chs   = (int*)(ws + OFF_CHS);
    unsigned short* wzt  = (unsigned short*)(ws + OFF_WZT);

    float2* carryB = (float2*)(ws + OFF_SCR);            // 524288 floats
    float2* cinArr = (float2*)(ws + OFF_SCR + 524288);   // 524288 floats

    hipLaunchKernelGGL(k_prep, dim3(577), dim3(512), 0, stream,
                       (const unsigned char*)start, (const int*)start, flags, chs,
                       Wz, wzt, x, W1, b1, W2, b2, Wgi, bgi, Wp, bp,
                       Wgo, bgo, Wsk, bsk, gated, go, sk);
    hipLaunchKernelGGL(k_scanA, dim3(512), dim3(512), 0, stream,
                       gated, flags, a, b, carryB);
    hipLaunchKernelGGL(k_scanC, dim3(64), dim3(64), 0, stream,
                       carryB, chs, a, b, st0, cinArr);
    hipLaunchKernelGGL(k_scanBZ, dim3(1024), dim3(256), 0, stream,
                       gated, flags, a, b, cinArr, wzt, part, out);
    hipLaunchKernelGGL(k_epi, dim3(1024), dim3(256), 0, stream,
                       part, bz, go, sk, W3, b3, W4, b4, out);
}